// Round 1
// baseline (569.832 us; speedup 1.0000x reference)
//
#include <hip/hip_runtime.h>
#include <stdint.h>

// QLinear HQQ 4-bit: out = x @ dequant(W_q).T + bias
// M=8192 tokens, N=4096 out features, K=4096 in features, group=64 along K.

typedef __attribute__((ext_vector_type(8))) _Float16 half8;
typedef __attribute__((ext_vector_type(4))) float f32x4;

#define M_DIM 8192
#define N_DIM 4096
#define K_DIM 4096

__device__ __forceinline__ void async16(const void* g, void* l) {
  // 16B/lane direct global->LDS. LDS dest is wave-uniform base + lane*16.
  __builtin_amdgcn_global_load_lds(
      (const __attribute__((address_space(1))) void*)g,
      (__attribute__((address_space(3))) void*)l,
      16, 0, 0);
}

// ---------------- stage 1a: x fp32 -> f16 ----------------
__global__ __launch_bounds__(256) void cvt_x_f16(const float* __restrict__ x,
                                                 _Float16* __restrict__ y) {
  const size_t i = ((size_t)blockIdx.x * 256 + threadIdx.x) * 8;
  f32x4 a = *(const f32x4*)(x + i);
  f32x4 b = *(const f32x4*)(x + i + 4);
  half8 h;
  h[0] = (_Float16)a[0]; h[1] = (_Float16)a[1];
  h[2] = (_Float16)a[2]; h[3] = (_Float16)a[3];
  h[4] = (_Float16)b[0]; h[5] = (_Float16)b[1];
  h[6] = (_Float16)b[2]; h[7] = (_Float16)b[3];
  *(half8*)(y + i) = h;
}

// ---------------- stage 1b: dequant W_q -> f16 [N][K] ----------------
// W[o][k]: g = o*64 + k/64, j = k%64.
// o < 2048:  nib = (W_q[g][j] >> 4) & 0xF
// o >= 2048: nib = W_q[g - 131072][j] & 0xF
// W[o][k] = (nib - zero[g]) * scale[g]
__global__ __launch_bounds__(256) void deq_w_f16(const int* __restrict__ Wq,
                                                 const float* __restrict__ scale,
                                                 const float* __restrict__ zero,
                                                 _Float16* __restrict__ W) {
  const int idx = blockIdx.x * 256 + threadIdx.x;   // 0..2097151, 8 elems each
  const int o  = idx >> 9;                          // row 0..4095
  const int kb = (idx & 511) << 3;                  // col start, step 8
  const int g  = (o << 6) + (kb >> 6);              // group id into scale/zero
  const int j  = kb & 63;                           // j..j+7 all in same group
  const bool hi = (o < 2048);
  const int* src = Wq + (size_t)(hi ? g : g - 131072) * 64 + j;
  const int4 v0 = *(const int4*)src;
  const int4 v1 = *(const int4*)(src + 4);
  const float s  = scale[g];
  const float nz = -zero[g] * s;                    // (nib - z)*s = nib*s + nz
  int raw[8] = {v0.x, v0.y, v0.z, v0.w, v1.x, v1.y, v1.z, v1.w};
  half8 h;
#pragma unroll
  for (int r = 0; r < 8; ++r) {
    const int nib = hi ? ((raw[r] >> 4) & 0xF) : (raw[r] & 0xF);
    h[r] = (_Float16)((float)nib * s + nz);
  }
  *(half8*)(W + (size_t)o * K_DIM + kb) = h;
}

// ---------------- stage 2: f16 MFMA GEMM-BT (m97 structure) ----------------
// C[m][n] = sum_k A[m][k] * B[n][k] + bias[n].  A:[M][K] f16, B:[N][K] f16.
// Block tile 128x128, BK=32, 256 threads = 4 waves, each wave a 64x64 quadrant
// (4x4 grid of 16x16x32 MFMAs).
__global__ __launch_bounds__(256) void gemm_f16_ws(const _Float16* __restrict__ A,
                                                   const _Float16* __restrict__ B,
                                                   const float* __restrict__ bias,
                                                   float* __restrict__ C) {
  __shared__ _Float16 As[128 * 32];   // 8 KB
  __shared__ _Float16 Bs[128 * 32];   // 8 KB

  const int tid  = threadIdx.x;
  const int wave = tid >> 6;
  const int lane = tid & 63;
  const int quad = lane >> 4;
  const int l16  = lane & 15;

  const int m0 = blockIdx.y * 128;
  const int n0 = blockIdx.x * 128;
  const int wm = (wave & 1) * 64;
  const int wn = (wave >> 1) * 64;

  // staging: thread t owns LDS elements t*8..t*8+7 => row t/4, col (t%4)*8
  const int srow = tid >> 2;
  const int scol = (tid & 3) << 3;
  const _Float16* gA0 = A + (size_t)(m0 + srow) * K_DIM + scol;
  const _Float16* gA1 = gA0 + (size_t)64 * K_DIM;
  const _Float16* gB0 = B + (size_t)(n0 + srow) * K_DIM + scol;
  const _Float16* gB1 = gB0 + (size_t)64 * K_DIM;
  _Float16* ldsA = As + wave * 512;   // wave-uniform base, 512 halfs = 1024 B
  _Float16* ldsB = Bs + wave * 512;

  f32x4 acc[4][4] = {};

  for (int k0 = 0; k0 < K_DIM; k0 += 32) {
    __syncthreads();                      // prev tile fully consumed
    async16(gA0 + k0, ldsA);              // A rows 0..63 of tile
    async16(gA1 + k0, ldsA + 2048);       // A rows 64..127
    async16(gB0 + k0, ldsB);
    async16(gB1 + k0, ldsB + 2048);
    __syncthreads();                      // vmcnt(0) drain before barrier

    half8 aF[4], bF[4];
#pragma unroll
    for (int i = 0; i < 4; ++i)
      aF[i] = *(const half8*)(As + (wm + i * 16 + l16) * 32 + quad * 8);
#pragma unroll
    for (int j = 0; j < 4; ++j)
      bF[j] = *(const half8*)(Bs + (wn + j * 16 + l16) * 32 + quad * 8);
#pragma unroll
    for (int i = 0; i < 4; ++i)
#pragma unroll
      for (int j = 0; j < 4; ++j)
        acc[i][j] = __builtin_amdgcn_mfma_f32_16x16x32_f16(aF[i], bF[j],
                                                           acc[i][j], 0, 0, 0);
  }

  // epilogue: D row = quad*4 + reg, col = l16
#pragma unroll
  for (int j = 0; j < 4; ++j) {
    const int n = n0 + wn + j * 16 + l16;
    const float bv = bias[n];
#pragma unroll
    for (int i = 0; i < 4; ++i) {
      const int m = m0 + wm + i * 16 + quad * 4;
      float* p = C + (size_t)m * N_DIM + n;
      f32x4 v = acc[i][j];
      p[0 * N_DIM] = v[0] + bv;
      p[1 * N_DIM] = v[1] + bv;
      p[2 * N_DIM] = v[2] + bv;
      p[3 * N_DIM] = v[3] + bv;
    }
  }
}

// ---------------- fallback: fused fp32 GEMM, no workspace ----------------
// 64x64 tile, BK=16, 256 threads, 4x4 outputs/thread. Correctness-first.
__global__ __launch_bounds__(256) void gemm_fp32_fallback(
    const float* __restrict__ x, const int* __restrict__ Wq,
    const float* __restrict__ scale, const float* __restrict__ zero,
    const float* __restrict__ bias, float* __restrict__ C) {
  __shared__ float As[64][16];
  __shared__ float Bs[64][16];
  const int tid = threadIdx.x;
  const int m0 = blockIdx.y * 64;
  const int n0 = blockIdx.x * 64;
  const int tx = tid & 15;        // n direction
  const int ty = tid >> 4;        // m direction
  const int lr = tid >> 2;        // staging row 0..63
  const int lc = (tid & 3) << 2;  // staging col 0,4,8,12

  float acc[4][4] = {};

  for (int k0 = 0; k0 < K_DIM; k0 += 16) {
    __syncthreads();
    *(f32x4*)&As[lr][lc] = *(const f32x4*)(x + (size_t)(m0 + lr) * K_DIM + k0 + lc);
    {
      const int o = n0 + lr;
      const int k = k0 + lc;
      const int g = (o << 6) + (k >> 6);
      const bool hi = (o < 2048);
      const int* src = Wq + (size_t)(hi ? g : g - 131072) * 64 + (k & 63);
      const int4 v = *(const int4*)src;
      const float s = scale[g];
      const float nz = -zero[g] * s;
      f32x4 b;
      if (hi) {
        b[0] = (float)((v.x >> 4) & 0xF) * s + nz;
        b[1] = (float)((v.y >> 4) & 0xF) * s + nz;
        b[2] = (float)((v.z >> 4) & 0xF) * s + nz;
        b[3] = (float)((v.w >> 4) & 0xF) * s + nz;
      } else {
        b[0] = (float)(v.x & 0xF) * s + nz;
        b[1] = (float)(v.y & 0xF) * s + nz;
        b[2] = (float)(v.z & 0xF) * s + nz;
        b[3] = (float)(v.w & 0xF) * s + nz;
      }
      *(f32x4*)&Bs[lr][lc] = b;
    }
    __syncthreads();
#pragma unroll
    for (int kk = 0; kk < 16; ++kk) {
      float a[4], b[4];
#pragma unroll
      for (int r = 0; r < 4; ++r) a[r] = As[ty * 4 + r][kk];
#pragma unroll
      for (int c = 0; c < 4; ++c) b[c] = Bs[tx * 4 + c][kk];
#pragma unroll
      for (int r = 0; r < 4; ++r)
#pragma unroll
        for (int c = 0; c < 4; ++c) acc[r][c] += a[r] * b[c];
    }
  }
#pragma unroll
  for (int r = 0; r < 4; ++r)
#pragma unroll
    for (int c = 0; c < 4; ++c) {
      const int n = n0 + tx * 4 + c;
      C[(size_t)(m0 + ty * 4 + r) * N_DIM + n] = acc[r][c] + bias[n];
    }
}

extern "C" void kernel_launch(void* const* d_in, const int* in_sizes, int n_in,
                              void* d_out, int out_size, void* d_ws, size_t ws_size,
                              hipStream_t stream) {
  const float* x     = (const float*)d_in[0];
  const int*   Wq    = (const int*)d_in[1];
  const float* scale = (const float*)d_in[2];
  const float* zero  = (const float*)d_in[3];
  const float* bias  = (const float*)d_in[4];
  float* out = (float*)d_out;

  const size_t xh_bytes = (size_t)M_DIM * K_DIM * 2;  // 64 MB
  const size_t wh_bytes = (size_t)N_DIM * K_DIM * 2;  // 32 MB

  if (ws_size >= xh_bytes + wh_bytes) {
    _Float16* xh = (_Float16*)d_ws;
    _Float16* wh = (_Float16*)((char*)d_ws + xh_bytes);
    cvt_x_f16<<<M_DIM * K_DIM / (256 * 8), 256, 0, stream>>>(x, xh);
    deq_w_f16<<<N_DIM * K_DIM / (256 * 8), 256, 0, stream>>>(Wq, scale, zero, wh);
    dim3 grid(N_DIM / 128, M_DIM / 128);  // (32, 64)
    gemm_f16_ws<<<grid, 256, 0, stream>>>(xh, wh, bias, out);
  } else {
    dim3 grid(N_DIM / 64, M_DIM / 64);    // (64, 128)
    gemm_fp32_fallback<<<grid, 256, 0, stream>>>(x, Wq, scale, zero, bias, out);
  }
}

// Round 2
// 560.685 us; speedup vs baseline: 1.0163x; 1.0163x over previous
//
#include <hip/hip_runtime.h>
#include <stdint.h>

// QLinear HQQ 4-bit: out = x @ dequant(W_q).T + bias
// M=8192 tokens, N=4096 out features, K=4096 in features, group=64 along K.
//
// R2: XOR-swizzle LDS granules to kill the 3.35e7 bank conflicts seen in R1.
// Fragment-read starting bank was (l16&1)*16 + quad*4 -> 4-way conflict per
// 8-lane phase. Swizzle: physical 16B-granule = logical ^ ((row>>1)&3),
// implemented by permuting the GLOBAL source granule each lane fetches
// (global_load_lds pins lane->LDS slot, so we permute the fetch side).

typedef __attribute__((ext_vector_type(8))) _Float16 half8;
typedef __attribute__((ext_vector_type(4))) float f32x4;

#define M_DIM 8192
#define N_DIM 4096
#define K_DIM 4096

__device__ __forceinline__ void async16(const void* g, void* l) {
  // 16B/lane direct global->LDS. LDS dest is wave-uniform base + lane*16.
  __builtin_amdgcn_global_load_lds(
      (const __attribute__((address_space(1))) void*)g,
      (__attribute__((address_space(3))) void*)l,
      16, 0, 0);
}

// ---------------- stage 1a: x fp32 -> f16 ----------------
__global__ __launch_bounds__(256) void cvt_x_f16(const float* __restrict__ x,
                                                 _Float16* __restrict__ y) {
  const size_t i = ((size_t)blockIdx.x * 256 + threadIdx.x) * 8;
  f32x4 a = *(const f32x4*)(x + i);
  f32x4 b = *(const f32x4*)(x + i + 4);
  half8 h;
  h[0] = (_Float16)a[0]; h[1] = (_Float16)a[1];
  h[2] = (_Float16)a[2]; h[3] = (_Float16)a[3];
  h[4] = (_Float16)b[0]; h[5] = (_Float16)b[1];
  h[6] = (_Float16)b[2]; h[7] = (_Float16)b[3];
  *(half8*)(y + i) = h;
}

// ---------------- stage 1b: dequant W_q -> f16 [N][K] ----------------
// W[o][k]: g = o*64 + k/64, j = k%64.
// o < 2048:  nib = (W_q[g][j] >> 4) & 0xF
// o >= 2048: nib = W_q[g - 131072][j] & 0xF
__global__ __launch_bounds__(256) void deq_w_f16(const int* __restrict__ Wq,
                                                 const float* __restrict__ scale,
                                                 const float* __restrict__ zero,
                                                 _Float16* __restrict__ W) {
  const int idx = blockIdx.x * 256 + threadIdx.x;   // 0..2097151, 8 elems each
  const int o  = idx >> 9;                          // row 0..4095
  const int kb = (idx & 511) << 3;                  // col start, step 8
  const int g  = (o << 6) + (kb >> 6);              // group id into scale/zero
  const int j  = kb & 63;                           // j..j+7 all in same group
  const bool hi = (o < 2048);
  const int* src = Wq + (size_t)(hi ? g : g - 131072) * 64 + j;
  const int4 v0 = *(const int4*)src;
  const int4 v1 = *(const int4*)(src + 4);
  const float s  = scale[g];
  const float nz = -zero[g] * s;                    // (nib - z)*s = nib*s + nz
  int raw[8] = {v0.x, v0.y, v0.z, v0.w, v1.x, v1.y, v1.z, v1.w};
  half8 h;
#pragma unroll
  for (int r = 0; r < 8; ++r) {
    const int nib = hi ? ((raw[r] >> 4) & 0xF) : (raw[r] & 0xF);
    h[r] = (_Float16)((float)nib * s + nz);
  }
  *(half8*)(W + (size_t)o * K_DIM + kb) = h;
}

// ---------------- stage 2: f16 MFMA GEMM-BT, swizzled LDS ----------------
// C[m][n] = sum_k A[m][k] * B[n][k] + bias[n].  A:[M][K] f16, B:[N][K] f16.
// Block tile 128x128, BK=32, 256 threads = 4 waves, each wave a 64x64 quadrant
// (4x4 grid of 16x16x32 MFMAs). LDS granule swizzle: phys = log ^ ((row>>1)&3).
__global__ __launch_bounds__(256) void gemm_f16_ws(const _Float16* __restrict__ A,
                                                   const _Float16* __restrict__ B,
                                                   const float* __restrict__ bias,
                                                   float* __restrict__ C) {
  __shared__ _Float16 As[128 * 32];   // 8 KB
  __shared__ _Float16 Bs[128 * 32];   // 8 KB

  const int tid  = threadIdx.x;
  const int wave = tid >> 6;
  const int lane = tid & 63;
  const int quad = lane >> 4;
  const int l16  = lane & 15;

  const int m0 = blockIdx.y * 128;
  const int n0 = blockIdx.x * 128;
  const int wm = (wave & 1) * 64;
  const int wn = (wave >> 1) * 64;

  // staging: thread t's 16B lands at LDS granule t (row t/4, phys granule t%4).
  // Fetch the LOGICAL granule (t%4) ^ swz(row) so reads can un-swizzle.
  const int srow = tid >> 2;
  const int scol = (((tid & 3) ^ ((tid >> 3) & 3)) << 3);  // swizzled col start
  const _Float16* gA0 = A + (size_t)(m0 + srow) * K_DIM + scol;
  const _Float16* gA1 = gA0 + (size_t)64 * K_DIM;
  const _Float16* gB0 = B + (size_t)(n0 + srow) * K_DIM + scol;
  const _Float16* gB1 = gB0 + (size_t)64 * K_DIM;
  _Float16* ldsA = As + wave * 512;   // wave-uniform base, 512 halfs = 1024 B
  _Float16* ldsB = Bs + wave * 512;

  const int swz = (l16 >> 1) & 3;     // row-derived swizzle for fragment reads
  const int gA_off = ((quad ^ swz) << 3);  // un-swizzled granule byte offset/2

  f32x4 acc[4][4] = {};

  for (int k0 = 0; k0 < K_DIM; k0 += 32) {
    __syncthreads();                      // prev tile fully consumed
    async16(gA0 + k0, ldsA);              // A rows 0..63 of tile
    async16(gA1 + k0, ldsA + 2048);       // A rows 64..127
    async16(gB0 + k0, ldsB);
    async16(gB1 + k0, ldsB + 2048);
    __syncthreads();                      // vmcnt(0) drain before barrier

    half8 aF[4], bF[4];
#pragma unroll
    for (int i = 0; i < 4; ++i)
      aF[i] = *(const half8*)(As + (wm + i * 16 + l16) * 32 + gA_off);
#pragma unroll
    for (int j = 0; j < 4; ++j)
      bF[j] = *(const half8*)(Bs + (wn + j * 16 + l16) * 32 + gA_off);
#pragma unroll
    for (int i = 0; i < 4; ++i)
#pragma unroll
      for (int j = 0; j < 4; ++j)
        acc[i][j] = __builtin_amdgcn_mfma_f32_16x16x32_f16(aF[i], bF[j],
                                                           acc[i][j], 0, 0, 0);
  }

  // epilogue: D row = quad*4 + reg, col = l16
#pragma unroll
  for (int j = 0; j < 4; ++j) {
    const int n = n0 + wn + j * 16 + l16;
    const float bv = bias[n];
#pragma unroll
    for (int i = 0; i < 4; ++i) {
      const int m = m0 + wm + i * 16 + quad * 4;
      float* p = C + (size_t)m * N_DIM + n;
      f32x4 v = acc[i][j];
      p[0 * N_DIM] = v[0] + bv;
      p[1 * N_DIM] = v[1] + bv;
      p[2 * N_DIM] = v[2] + bv;
      p[3 * N_DIM] = v[3] + bv;
    }
  }
}

// ---------------- fallback: fused fp32 GEMM, no workspace ----------------
__global__ __launch_bounds__(256) void gemm_fp32_fallback(
    const float* __restrict__ x, const int* __restrict__ Wq,
    const float* __restrict__ scale, const float* __restrict__ zero,
    const float* __restrict__ bias, float* __restrict__ C) {
  __shared__ float As[64][16];
  __shared__ float Bs[64][16];
  const int tid = threadIdx.x;
  const int m0 = blockIdx.y * 64;
  const int n0 = blockIdx.x * 64;
  const int tx = tid & 15;
  const int ty = tid >> 4;
  const int lr = tid >> 2;
  const int lc = (tid & 3) << 2;

  float acc[4][4] = {};

  for (int k0 = 0; k0 < K_DIM; k0 += 16) {
    __syncthreads();
    *(f32x4*)&As[lr][lc] = *(const f32x4*)(x + (size_t)(m0 + lr) * K_DIM + k0 + lc);
    {
      const int o = n0 + lr;
      const int k = k0 + lc;
      const int g = (o << 6) + (k >> 6);
      const bool hi = (o < 2048);
      const int* src = Wq + (size_t)(hi ? g : g - 131072) * 64 + (k & 63);
      const int4 v = *(const int4*)src;
      const float s = scale[g];
      const float nz = -zero[g] * s;
      f32x4 b;
      if (hi) {
        b[0] = (float)((v.x >> 4) & 0xF) * s + nz;
        b[1] = (float)((v.y >> 4) & 0xF) * s + nz;
        b[2] = (float)((v.z >> 4) & 0xF) * s + nz;
        b[3] = (float)((v.w >> 4) & 0xF) * s + nz;
      } else {
        b[0] = (float)(v.x & 0xF) * s + nz;
        b[1] = (float)(v.y & 0xF) * s + nz;
        b[2] = (float)(v.z & 0xF) * s + nz;
        b[3] = (float)(v.w & 0xF) * s + nz;
      }
      *(f32x4*)&Bs[lr][lc] = b;
    }
    __syncthreads();
#pragma unroll
    for (int kk = 0; kk < 16; ++kk) {
      float a[4], b[4];
#pragma unroll
      for (int r = 0; r < 4; ++r) a[r] = As[ty * 4 + r][kk];
#pragma unroll
      for (int c = 0; c < 4; ++c) b[c] = Bs[tx * 4 + c][kk];
#pragma unroll
      for (int r = 0; r < 4; ++r)
#pragma unroll
        for (int c = 0; c < 4; ++c) acc[r][c] += a[r] * b[c];
    }
  }
#pragma unroll
  for (int r = 0; r < 4; ++r)
#pragma unroll
    for (int c = 0; c < 4; ++c) {
      const int n = n0 + tx * 4 + c;
      C[(size_t)(m0 + ty * 4 + r) * N_DIM + n] = acc[r][c] + bias[n];
    }
}

extern "C" void kernel_launch(void* const* d_in, const int* in_sizes, int n_in,
                              void* d_out, int out_size, void* d_ws, size_t ws_size,
                              hipStream_t stream) {
  const float* x     = (const float*)d_in[0];
  const int*   Wq    = (const int*)d_in[1];
  const float* scale = (const float*)d_in[2];
  const float* zero  = (const float*)d_in[3];
  const float* bias  = (const float*)d_in[4];
  float* out = (float*)d_out;

  const size_t xh_bytes = (size_t)M_DIM * K_DIM * 2;  // 64 MB
  const size_t wh_bytes = (size_t)N_DIM * K_DIM * 2;  // 32 MB

  if (ws_size >= xh_bytes + wh_bytes) {
    _Float16* xh = (_Float16*)d_ws;
    _Float16* wh = (_Float16*)((char*)d_ws + xh_bytes);
    cvt_x_f16<<<M_DIM * K_DIM / (256 * 8), 256, 0, stream>>>(x, xh);
    deq_w_f16<<<N_DIM * K_DIM / (256 * 8), 256, 0, stream>>>(Wq, scale, zero, wh);
    dim3 grid(N_DIM / 128, M_DIM / 128);  // (32, 64)
    gemm_f16_ws<<<grid, 256, 0, stream>>>(xh, wh, bias, out);
  } else {
    dim3 grid(N_DIM / 64, M_DIM / 64);    // (64, 128)
    gemm_fp32_fallback<<<grid, 256, 0, stream>>>(x, Wq, scale, zero, bias, out);
  }
}